// Round 4
// baseline (21290.286 us; speedup 1.0000x reference)
//
#include <hip/hip_runtime.h>

// ---------------------------------------------------------------------------
// VRAE LSTM: B=512, T=512, HE=HD=512, L=64.
// 16 groups x 16 WGs; group = 32 batch rows, WG = 32 hidden units (128 gate cols).
// U slice in registers (AGPR/VGPR) as f16 MFMA B-fragments, pinned via asm.
// Cross-WG h exchange via relaxed agent-scope atomics; group h tile staged to
// LDS each step. This round: XCD-local group placement + 3 ablation probes
// (VAR=1 nosync / VAR=2 nostage / VAR=3 synconly) to split the 7.5us/step.
// ---------------------------------------------------------------------------

#define B_  512
#define T_  512
#define H_  512
#define NG  16
#define WPG 16
#define BPG 32
#define UPW 32

typedef _Float16 f16;
typedef _Float16 f16x8 __attribute__((ext_vector_type(8)));
typedef _Float16 f16x4 __attribute__((ext_vector_type(4)));
typedef float f32x16 __attribute__((ext_vector_type(16)));
typedef unsigned long long u64;

// d_out layout (floats): mu_dec[512*512] | sg_dec[512*512] | mu_enc[512*64] | sg_enc[512*64]
#define OFF_SG_DEC 262144
#define OFF_MU_ENC 524288
#define OFF_SG_ENC 557056

__device__ __forceinline__ float sigm_(float x) { return 1.f / (1.f + __expf(-x)); }
__device__ __forceinline__ float tanh_(float x) {
  float t = fabsf(x);
  float e = __expf(2.f * t);
  float r = 1.f - 2.f / (e + 1.f);
  return x < 0.f ? -r : r;
}
__device__ __forceinline__ float softplus_(float x) {
  return fmaxf(x, 0.f) + log1pf(__expf(-fabsf(x)));
}

// ---------------------------------------------------------------------------
// Recurrent kernel.  IS_DEC=0: encoder (xin = input [B][T], gw=enc_W, gb=enc_b)
//                    IS_DEC=1: decoder (xin = zin [B][2048] incl bias, gw=dmu_W, gb=dstd_W)
// VAR: 0=real, 1=nosync probe, 2=nostage probe, 3=synconly probe.
// hbuf: [2][512][512] f16 (double-buffered h); flags: [16 g][16 wg][32 ints]
// ---------------------------------------------------------------------------
template <int IS_DEC, int VAR>
__global__ void __launch_bounds__(256, 1)
lstm_rec(const float* __restrict__ U,     // [512][2048]
         const float* __restrict__ xin,
         const float* __restrict__ gw,
         const float* __restrict__ gb,
         f16* __restrict__ hbuf,
         float* __restrict__ accmu,
         float* __restrict__ accsg,
         int* __restrict__ flags,
         int T) {
  const int bid = blockIdx.x;
  // XCD-local placement: assuming dispatch XCD = bid%8, all 16 WGs of a group
  // share one residue -> one XCD (2 groups per XCD).
  const int g = (bid & 7) * 2 + (bid >> 7);   // group 0..15
  const int wg = (bid >> 3) & 15;             // hidden-slice within group
  const int tid = threadIdx.x;
  const int wave = tid >> 6, lane = tid & 63;
  const int B0 = g * BPG;
  const int U0 = wg * UPW;

  // ---------------- B fragments (U slice) into registers, f16 -----------------
  const int ccol = lane & 31, khalf = lane >> 5;
  const int uu = ccol >> 2, gate = ccol & 3;
  const int gc = gate * 512 + U0 + wave * 8 + uu;  // global gate column in [0,2048)
  f16x8 Breg[32];
#pragma unroll
  for (int ks = 0; ks < 32; ++ks) {
    f16x8 bb;
#pragma unroll
    for (int j = 0; j < 8; ++j)
      bb[j] = (f16)U[(ks * 16 + khalf * 8 + j) * 2048 + gc];
    Breg[ks] = bb;
  }
#pragma unroll
  for (int ks = 0; ks < 32; ++ks) asm volatile("" : "+v"(Breg[ks]));

  // ---------------- per-thread elementwise mapping ----------------------------
  const int brow = tid & 31;  // batch row within group
  const int us = tid >> 5;    // unit slice 0..7 (4 units each)
  float addv[16], xw[16], dmur[4], dstdr[4];
#pragma unroll
  for (int m = 0; m < 4; ++m) {
    const int q = us * 4 + m;
#pragma unroll
    for (int gt = 0; gt < 4; ++gt) {
      const int col = gt * 512 + U0 + q;
      if (IS_DEC) {
        addv[m * 4 + gt] = xin[(B0 + brow) * 2048 + col];
        xw[m * 4 + gt] = 0.f;
      } else {
        addv[m * 4 + gt] = gb[col];
        xw[m * 4 + gt] = gw[col];
      }
    }
    if (IS_DEC) {
      dmur[m] = gw[U0 + q];
      dstdr[m] = gb[U0 + q];
    } else {
      dmur[m] = 0.f;
      dstdr[m] = 0.f;
    }
  }

  float cst[4] = {0.f, 0.f, 0.f, 0.f};

  __shared__ f16 hstage[32 * 520];         // 33,280 B
  __shared__ float gatesLds[4 * 32 * 33];  // 16,896 B
  __shared__ float pmuLds[32 * 9];
  __shared__ float psgLds[32 * 9];

  const int arow = lane & 31;
  int* const myflag = &flags[(g * WPG + wg) * 32];
  int* const grpflags = &flags[(g * WPG) * 32];

  for (int t = 0; t < T; ++t) {
    // ------------------ stage group h tile (32KB) -> LDS -----------------
    const u64* hsrc64 =
        (const u64*)(hbuf + (t & 1) * (NG * BPG * H_) + B0 * H_);
    float xv = 0.f;
    if (!IS_DEC && VAR != 3) xv = xin[(B0 + brow) * T_ + (t & (T_ - 1))];
    if (VAR == 0 || VAR == 1 || (VAR == 2 && t == 0)) {
#pragma unroll
      for (int i = 0; i < 16; ++i) {
        const int w = tid + i * 256;   // 8B word; 128 u64 per 512-f16 row
        const int row = w >> 7;
        const int c8 = w & 127;
        u64 v = __hip_atomic_load(hsrc64 + w, __ATOMIC_RELAXED,
                                  __HIP_MEMORY_SCOPE_AGENT);
        *(u64*)&hstage[row * 520 + c8 * 4] = v;
      }
    }
    __syncthreads();

    union { f16x4 h4; u64 u; } cv;
    if (VAR != 3) {
      // ------------------ gates = h @ U (MFMA, B in regs) ----------------
      f32x16 acc;
#pragma unroll
      for (int j = 0; j < 16; ++j) acc[j] = 0.f;
#pragma unroll
      for (int ks = 0; ks < 32; ++ks) {
        f16x8 a = *(const f16x8*)&hstage[arow * 520 + ks * 16 + khalf * 8];
        acc = __builtin_amdgcn_mfma_f32_32x32x16_f16(a, Breg[ks], acc, 0, 0, 0);
      }
#pragma unroll
      for (int r = 0; r < 16; ++r) {
        const int row = 4 * (lane >> 5) + (r & 3) + 8 * (r >> 2);
        gatesLds[wave * (32 * 33) + row * 33 + ccol] = acc[r];
      }
      __syncthreads();

      // ------------------ elementwise LSTM update ------------------------
      float hn[4];
#pragma unroll
      for (int m = 0; m < 4; ++m) {
        const int q = us * 4 + m;
        const int wsrc = q >> 3;
        const int uu2 = q & 7;
        float ga[4];
#pragma unroll
        for (int gt = 0; gt < 4; ++gt) {
          float v = gatesLds[wsrc * (32 * 33) + brow * 33 + uu2 * 4 + gt];
          v += addv[m * 4 + gt];
          if (!IS_DEC) v += xv * xw[m * 4 + gt];
          ga[gt] = v;
        }
        const float iv = sigm_(ga[0]);
        const float fv = sigm_(ga[1]);
        const float gv = tanh_(ga[2]);
        const float ov = sigm_(ga[3]);
        const float cn = fv * cst[m] + iv * gv;
        cst[m] = cn;
        hn[m] = ov * tanh_(cn);
      }
#pragma unroll
      for (int m = 0; m < 4; ++m) cv.h4[m] = (f16)hn[m];

      if (IS_DEC) {
        float pmu = 0.f, psg = 0.f;
#pragma unroll
        for (int m = 0; m < 4; ++m) {
          pmu += hn[m] * dmur[m];
          psg += hn[m] * dstdr[m];
        }
        pmuLds[brow * 9 + us] = pmu;
        psgLds[brow * 9 + us] = psg;
      }
    } else {
      cv.u = (u64)t * 0x0001000100010001ull;  // synconly: arbitrary payload
    }

    // store h_new (next buffer) as one 8B LLC-coherent store
    f16* hdst = hbuf + ((t + 1) & 1) * (NG * BPG * H_) + (B0 + brow) * H_ + U0 + us * 4;
    __hip_atomic_store((u64*)hdst, cv.u, __ATOMIC_RELAXED,
                       __HIP_MEMORY_SCOPE_AGENT);

    if (VAR != 1) {
      // ---------------- release: h stores acked at LLC, then flag --------
      asm volatile("s_waitcnt vmcnt(0)" ::: "memory");
      __syncthreads();
      if (t + 1 < T && tid == 0)
        __hip_atomic_store(myflag, t + 1, __ATOMIC_RELAXED,
                           __HIP_MEMORY_SCOPE_AGENT);
    }

    if (IS_DEC && VAR == 0) {  // off the critical path
      if (tid < 32) {
        float s = 0.f;
#pragma unroll
        for (int j = 0; j < 8; ++j) s += pmuLds[tid * 9 + j];
        unsafeAtomicAdd(&accmu[(B0 + tid) * T_ + t], s);
      } else if (tid < 64) {
        const int rr = tid - 32;
        float s = 0.f;
#pragma unroll
        for (int j = 0; j < 8; ++j) s += psgLds[rr * 9 + j];
        unsafeAtomicAdd(&accsg[(B0 + rr) * T_ + t], s);
      }
    }

    if (VAR != 1) {
      // ---------------- group barrier: poll 16 flags ---------------------
      if (t + 1 < T) {
        if (tid < WPG) {
          while (__hip_atomic_load(&grpflags[tid * 32], __ATOMIC_RELAXED,
                                   __HIP_MEMORY_SCOPE_AGENT) < t + 1) {
          }
        }
        __syncthreads();
      }
    }
  }
}

// ---------------------------------------------------------------------------
__global__ void enc_heads(const f16* __restrict__ h0, const float* __restrict__ emuW,
                          const float* __restrict__ emub, const float* __restrict__ estdW,
                          const float* __restrict__ estdb, float* __restrict__ out,
                          float* __restrict__ z) {
  const int b = blockIdx.x, tid = threadIdx.x;
  __shared__ float hrow[512];
  for (int k = tid; k < 512; k += 128)
    hrow[k] = (float)h0[b * H_ + k];
  __syncthreads();
  const int head = tid >> 6, l = tid & 63;
  const float* W = head ? estdW : emuW;
  float a = 0.f;
#pragma unroll 8
  for (int k = 0; k < 512; ++k) a += hrow[k] * W[k * 64 + l];
  if (head == 0) {
    const float v = a + emub[l];
    out[OFF_MU_ENC + b * 64 + l] = v;
    z[b * 64 + l] = v;
  } else {
    out[OFF_SG_ENC + b * 64 + l] = softplus_(a + estdb[l]);
  }
}

// ---------------------------------------------------------------------------
__global__ void dec_prep(const float* __restrict__ z, const float* __restrict__ dfsW,
                         const float* __restrict__ dfsb, const float* __restrict__ decW,
                         const float* __restrict__ decb, f16* __restrict__ hbuf,
                         float* __restrict__ zin) {
  const int b = blockIdx.x, tid = threadIdx.x;
  __shared__ float zl[64];
  if (tid < 64) zl[tid] = z[b * 64 + tid];
  __syncthreads();
  for (int c = tid; c < 512; c += 256) {
    float a = dfsb[c];
#pragma unroll
    for (int l = 0; l < 64; ++l) a += zl[l] * dfsW[l * 512 + c];
    hbuf[b * H_ + c] = (f16)tanh_(a);
  }
  for (int c = tid; c < 2048; c += 256) {
    float a = decb[c];
#pragma unroll
    for (int l = 0; l < 64; ++l) a += zl[l] * decW[l * 2048 + c];
    zin[b * 2048 + c] = a;
  }
}

// ---------------------------------------------------------------------------
__global__ void finalize_k(const float* __restrict__ accmu, const float* __restrict__ accsg,
                           const float* __restrict__ dmub, const float* __restrict__ dstdb,
                           float* __restrict__ out) {
  const int i = blockIdx.x * 256 + threadIdx.x;
  out[i] = accmu[i] + dmub[0];
  out[OFF_SG_DEC + i] = softplus_(accsg[i] + dstdb[0]);
}

// ---------------------------------------------------------------------------
extern "C" void kernel_launch(void* const* d_in, const int* in_sizes, int n_in,
                              void* d_out, int out_size, void* d_ws, size_t ws_size,
                              hipStream_t stream) {
  (void)in_sizes; (void)n_in; (void)out_size; (void)ws_size;
  const float* x     = (const float*)d_in[0];
  const float* encW  = (const float*)d_in[1];
  const float* encU  = (const float*)d_in[2];
  const float* encb  = (const float*)d_in[3];
  const float* emuW  = (const float*)d_in[4];
  const float* emub  = (const float*)d_in[5];
  const float* estdW = (const float*)d_in[6];
  const float* estdb = (const float*)d_in[7];
  const float* dfsW  = (const float*)d_in[8];
  const float* dfsb  = (const float*)d_in[9];
  const float* decW  = (const float*)d_in[10];
  const float* decU  = (const float*)d_in[11];
  const float* decb  = (const float*)d_in[12];
  const float* dmuW  = (const float*)d_in[13];
  const float* dmub  = (const float*)d_in[14];
  const float* dstdW = (const float*)d_in[15];
  const float* dstdb = (const float*)d_in[16];

  char* ws = (char*)d_ws;
  f16* hbuf    = (f16*)(ws + 0);                       // 1 MB: [2][512][512] f16
  float* accmu = (float*)(ws + (1u << 20));            // 1 MB
  float* accsg = (float*)(ws + (2u << 20));            // 1 MB
  int* flags   = (int*)(ws + (3u << 20));              // 64 KB (2 phases)
  float* zin   = (float*)(ws + (3u << 20) + 65536);    // 4 MB
  float* z     = (float*)(ws + (3u << 20) + 65536 + 512 * 2048 * 4);  // 128 KB
  float* out   = (float*)d_out;

  // Probe state overlaid on zin region (dec_prep rewrites it afterwards):
  f16* hbuf_p   = (f16*)zin;                           // 1 MB
  int* flags_p2 = (int*)((char*)zin + (1u << 20));     // 64 KB
  int* flags_p3 = (int*)((char*)zin + (1u << 20) + 65536);

  // zero hbuf/acc/flags + probe area (single contiguous memset)
  hipMemsetAsync(d_ws, 0, (3u << 20) + 65536 + (1u << 20) + 2 * 65536, stream);

  // ---- ablation probes (outputs unused; zin rewritten later) ----
  hipLaunchKernelGGL((lstm_rec<0, 1>), dim3(256), dim3(256), 0, stream,
                     encU, x, encW, encb, hbuf_p, nullptr, nullptr, flags_p2, 1024);
  hipLaunchKernelGGL((lstm_rec<0, 2>), dim3(256), dim3(256), 0, stream,
                     encU, x, encW, encb, hbuf_p, nullptr, nullptr, flags_p2, 1280);
  hipLaunchKernelGGL((lstm_rec<0, 3>), dim3(256), dim3(256), 0, stream,
                     encU, x, encW, encb, hbuf_p, nullptr, nullptr, flags_p3, 1536);

  // ---- real pipeline ----
  hipLaunchKernelGGL((lstm_rec<0, 0>), dim3(256), dim3(256), 0, stream,
                     encU, x, encW, encb, hbuf, (float*)nullptr, (float*)nullptr,
                     flags, T_);
  hipLaunchKernelGGL(enc_heads, dim3(512), dim3(128), 0, stream,
                     hbuf, emuW, emub, estdW, estdb, out, z);
  hipLaunchKernelGGL(dec_prep, dim3(512), dim3(256), 0, stream,
                     z, dfsW, dfsb, decW, decb, hbuf, zin);
  hipLaunchKernelGGL((lstm_rec<1, 0>), dim3(256), dim3(256), 0, stream,
                     decU, zin, dmuW, dstdW, hbuf, accmu, accsg,
                     flags + 16 * 16 * 32, T_);
  hipLaunchKernelGGL(finalize_k, dim3(1024), dim3(256), 0, stream,
                     accmu, accsg, dmub, dstdb, out);
}

// Round 5
// 4236.819 us; speedup vs baseline: 5.0251x; 5.0251x over previous
//
#include <hip/hip_runtime.h>

// ---------------------------------------------------------------------------
// VRAE LSTM: B=512, T=512, HE=HD=512, L=64.
// Decomposition: 32 groups (16 batch rows each) x 8 WGs (64 units each).
// WG = 512 threads (8 waves). Recurrent U pre-packed to f16 fragment order in
// ws; loaded into registers via asm-volatile global_load_dwordx4 (cannot be
// rematerialized -> truly resident, no per-step reload/convert).
// Cross-WG h exchange via relaxed agent-scope atomics (coherence point),
// group h tile (16KB) staged to LDS each step with 8 waves of latency hiding.
// ---------------------------------------------------------------------------

#define B_   512
#define T_   512
#define H_   512
#define NGR  32   // groups
#define WPG  8    // WGs per group
#define RPG  16   // batch rows per group
#define UPW  64   // units per WG

typedef _Float16 f16;
typedef _Float16 f16x8 __attribute__((ext_vector_type(8)));
typedef _Float16 f16x4 __attribute__((ext_vector_type(4)));
typedef float f32x16 __attribute__((ext_vector_type(16)));
typedef unsigned long long u64;

// d_out layout (floats): mu_dec[512*512] | sg_dec[512*512] | mu_enc[512*64] | sg_enc[512*64]
#define OFF_SG_DEC 262144
#define OFF_MU_ENC 524288
#define OFF_SG_ENC 557056

__device__ __forceinline__ float sigm_(float x) { return 1.f / (1.f + __expf(-x)); }
__device__ __forceinline__ float tanh_(float x) {
  float t = fabsf(x);
  float e = __expf(2.f * t);
  float r = 1.f - 2.f / (e + 1.f);
  return x < 0.f ? -r : r;
}
__device__ __forceinline__ float softplus_(float x) {
  return fmaxf(x, 0.f) + log1pf(__expf(-fabsf(x)));
}

// ---------------------------------------------------------------------------
// Pack U [512][2048] f32 -> Upk f16 in per-(wg,wave,ks,lane) fragment order:
// Upk[(((wg*8+w)*32+ks)<<9) + lane*8 + j] = U[k][gcol]
//   k = ks*16 + (lane>>5)*8 + j ; ccol=lane&31, uu=ccol>>2, gate=ccol&3,
//   gcol = gate*512 + wg*64 + w*8 + uu.
// ---------------------------------------------------------------------------
__global__ void pack_U(const float* __restrict__ U, f16* __restrict__ Upk) {
  const int e = blockIdx.x * 256 + threadIdx.x;  // 2^21 elements
  const int j = e & 7, lane = (e >> 3) & 63, ks = (e >> 9) & 31;
  const int w = (e >> 14) & 7, wg = (e >> 17) & 7;
  const int ccol = lane & 31, khalf = lane >> 5;
  const int uu = ccol >> 2, gate = ccol & 3;
  const int k = ks * 16 + khalf * 8 + j;
  const int gcol = gate * 512 + wg * UPW + w * 8 + uu;
  Upk[e] = (f16)U[k * 2048 + gcol];
}

// ---------------------------------------------------------------------------
// Recurrent kernel.  IS_DEC=0: encoder (xin=[B][T] input, gw=enc_W, gb=enc_b)
//                    IS_DEC=1: decoder (xin=zin [B][2048] incl bias, gw=dmu_W, gb=dstd_W)
// hbuf: [2][512][512] f16 double-buffered h; flags: [32 g][8 wg][32 ints]
// ---------------------------------------------------------------------------
template <int IS_DEC>
__global__ void __launch_bounds__(512, 1)
lstm_rec(const f16* __restrict__ Upk,
         const float* __restrict__ xin,
         const float* __restrict__ gw,
         const float* __restrict__ gb,
         f16* __restrict__ hbuf,
         float* __restrict__ accmu,
         float* __restrict__ accsg,
         int* __restrict__ flags) {
  const int bid = blockIdx.x;
  // XCD-local: assuming dispatch XCD = bid%8, a group's 8 WGs share one XCD.
  const int wg = (bid >> 3) & 7;
  const int g = (bid & 7) * 4 + (bid >> 6);  // 0..31
  const int tid = threadIdx.x;
  const int wave = tid >> 6, lane = tid & 63;
  const int R0 = g * RPG;    // global batch-row base
  const int U0 = wg * UPW;   // unit base

  // ---------------- B fragments from packed U: asm loads (non-remat) --------
  const int ccol = lane & 31, khalf = lane >> 5;
  f16x8 Breg[32];
#pragma unroll
  for (int ks = 0; ks < 32; ++ks) {
    const f16* p = Upk + (((wg * 8 + wave) * 32 + ks) << 9) + lane * 8;
    asm volatile("global_load_dwordx4 %0, %1, off\n\ts_waitcnt vmcnt(0)"
                 : "=v"(Breg[ks]) : "v"(p));
  }

  // ---------------- per-thread elementwise mapping (tid<256 active) ---------
  const int row = tid >> 4;        // 0..15 for active threads
  const int q = (tid & 15) * 4;    // first of 4 units
  float addv[16], xw[16], dmur[4], dstdr[4];
  if (tid < 256) {
#pragma unroll
    for (int m = 0; m < 4; ++m) {
#pragma unroll
      for (int gt = 0; gt < 4; ++gt) {
        const int col = gt * 512 + U0 + q + m;
        if (IS_DEC) {
          addv[m * 4 + gt] = xin[(R0 + row) * 2048 + col];
          xw[m * 4 + gt] = 0.f;
        } else {
          addv[m * 4 + gt] = gb[col];
          xw[m * 4 + gt] = gw[col];
        }
      }
      if (IS_DEC) {
        dmur[m] = gw[U0 + q + m];
        dstdr[m] = gb[U0 + q + m];
      } else {
        dmur[m] = 0.f;
        dstdr[m] = 0.f;
      }
    }
  }

  float cst[4] = {0.f, 0.f, 0.f, 0.f};

  __shared__ __align__(16) f16 hstage[RPG * 536];   // 17,152 B
  __shared__ float gatesLds[RPG * 260];             // 16,640 B
  __shared__ float pmuLds[RPG * 17];
  __shared__ float psgLds[RPG * 17];

  const int hrow = lane & 15;  // MFMA A row (dup for lanes 16-31 parity)
  int* const myflag = &flags[(g * WPG + wg) * 32];
  int* const grpflags = &flags[(g * WPG) * 32];

  for (int t = 0; t < T_; ++t) {
    // ------------------ stage group h tile (16KB) -> LDS -----------------
    const u64* hsrc64 = (const u64*)(hbuf + (t & 1) * (B_ * H_) + R0 * H_);
    float xv = 0.f;
    if (!IS_DEC && tid < 256) xv = xin[(R0 + row) * T_ + t];
#pragma unroll
    for (int i = 0; i < 4; ++i) {
      const int w = tid + i * 512;  // 2048 u64 total; 128 u64 per row
      const int r = w >> 7, c8 = w & 127;
      u64 v = __hip_atomic_load(hsrc64 + w, __ATOMIC_RELAXED,
                                __HIP_MEMORY_SCOPE_AGENT);
      *(u64*)&hstage[r * 536 + c8 * 4] = v;
    }
    __syncthreads();

    // ------------------ gates = h @ U (MFMA 32x32x16, B in regs) ---------
    f32x16 acc;
#pragma unroll
    for (int j = 0; j < 16; ++j) acc[j] = 0.f;
#pragma unroll
    for (int ks = 0; ks < 32; ++ks) {
      f16x8 a = *(const f16x8*)&hstage[hrow * 536 + ks * 16 + khalf * 8];
      acc = __builtin_amdgcn_mfma_f32_32x32x16_f16(a, Breg[ks], acc, 0, 0, 0);
    }
    // C rows 0..15 live in regs 0..7 (row=(r&3)+8*(r>>2)+4*khalf); drop rest.
#pragma unroll
    for (int r = 0; r < 8; ++r) {
      const int orow = (r & 3) + 8 * (r >> 2) + 4 * khalf;
      gatesLds[orow * 260 + wave * 32 + ccol] = acc[r];
    }
    __syncthreads();

    // ------------------ elementwise LSTM update (tid<256) ----------------
    union { f16x4 h4; u64 u; } cv;
    if (tid < 256) {
      float hn[4];
#pragma unroll
      for (int m = 0; m < 4; ++m) {
        float ga[4];
#pragma unroll
        for (int gt = 0; gt < 4; ++gt) {
          float v = gatesLds[row * 260 + (q + m) * 4 + gt] + addv[m * 4 + gt];
          if (!IS_DEC) v += xv * xw[m * 4 + gt];
          ga[gt] = v;
        }
        const float iv = sigm_(ga[0]);
        const float fv = sigm_(ga[1]);
        const float gv = tanh_(ga[2]);
        const float ov = sigm_(ga[3]);
        const float cn = fv * cst[m] + iv * gv;
        cst[m] = cn;
        hn[m] = ov * tanh_(cn);
      }
#pragma unroll
      for (int m = 0; m < 4; ++m) cv.h4[m] = (f16)hn[m];
      f16* hdst = hbuf + ((t + 1) & 1) * (B_ * H_) + (R0 + row) * H_ + U0 + q;
      __hip_atomic_store((u64*)hdst, cv.u, __ATOMIC_RELAXED,
                         __HIP_MEMORY_SCOPE_AGENT);
      if (IS_DEC) {
        float pmu = 0.f, psg = 0.f;
#pragma unroll
        for (int m = 0; m < 4; ++m) {
          pmu += (float)cv.h4[m] * dmur[m];
          psg += (float)cv.h4[m] * dstdr[m];
        }
        pmuLds[row * 17 + (tid & 15)] = pmu;
        psgLds[row * 17 + (tid & 15)] = psg;
      }
    }

    // ------------------ release: h stores acked at LLC, then flag --------
    asm volatile("s_waitcnt vmcnt(0)" ::: "memory");
    __syncthreads();
    if (t + 1 < T_ && tid == 0)
      __hip_atomic_store(myflag, t + 1, __ATOMIC_RELAXED,
                         __HIP_MEMORY_SCOPE_AGENT);

    if (IS_DEC) {  // head partial reduction, off the critical path
      if (tid < RPG) {
        float s = 0.f;
#pragma unroll
        for (int j = 0; j < 16; ++j) s += pmuLds[tid * 17 + j];
        unsafeAtomicAdd(&accmu[(R0 + tid) * T_ + t], s);
      } else if (tid < 2 * RPG) {
        const int rr = tid - RPG;
        float s = 0.f;
#pragma unroll
        for (int j = 0; j < 16; ++j) s += psgLds[rr * 17 + j];
        unsafeAtomicAdd(&accsg[(R0 + rr) * T_ + t], s);
      }
    }

    // ------------------ group barrier: poll 8 flags (relaxed + sleep) ----
    if (t + 1 < T_) {
      if (tid < WPG) {
        while (__hip_atomic_load(&grpflags[tid * 32], __ATOMIC_RELAXED,
                                 __HIP_MEMORY_SCOPE_AGENT) < t + 1) {
          asm volatile("s_sleep 1");
        }
      }
      __syncthreads();
    }
  }
}

// ---------------------------------------------------------------------------
__global__ void enc_heads(const f16* __restrict__ h0, const float* __restrict__ emuW,
                          const float* __restrict__ emub, const float* __restrict__ estdW,
                          const float* __restrict__ estdb, float* __restrict__ out,
                          float* __restrict__ z) {
  const int b = blockIdx.x, tid = threadIdx.x;
  __shared__ float hrow[512];
  for (int k = tid; k < 512; k += 128)
    hrow[k] = (float)h0[b * H_ + k];
  __syncthreads();
  const int head = tid >> 6, l = tid & 63;
  const float* W = head ? estdW : emuW;
  float a = 0.f;
#pragma unroll 8
  for (int k = 0; k < 512; ++k) a += hrow[k] * W[k * 64 + l];
  if (head == 0) {
    const float v = a + emub[l];
    out[OFF_MU_ENC + b * 64 + l] = v;
    z[b * 64 + l] = v;
  } else {
    out[OFF_SG_ENC + b * 64 + l] = softplus_(a + estdb[l]);
  }
}

// ---------------------------------------------------------------------------
__global__ void dec_prep(const float* __restrict__ z, const float* __restrict__ dfsW,
                         const float* __restrict__ dfsb, const float* __restrict__ decW,
                         const float* __restrict__ decb, f16* __restrict__ hbuf,
                         float* __restrict__ zin) {
  const int b = blockIdx.x, tid = threadIdx.x;
  __shared__ float zl[64];
  if (tid < 64) zl[tid] = z[b * 64 + tid];
  __syncthreads();
  for (int c = tid; c < 512; c += 256) {
    float a = dfsb[c];
#pragma unroll
    for (int l = 0; l < 64; ++l) a += zl[l] * dfsW[l * 512 + c];
    hbuf[b * H_ + c] = (f16)tanh_(a);
  }
  for (int c = tid; c < 2048; c += 256) {
    float a = decb[c];
#pragma unroll
    for (int l = 0; l < 64; ++l) a += zl[l] * decW[l * 2048 + c];
    zin[b * 2048 + c] = a;
  }
}

// ---------------------------------------------------------------------------
__global__ void finalize_k(const float* __restrict__ accmu, const float* __restrict__ accsg,
                           const float* __restrict__ dmub, const float* __restrict__ dstdb,
                           float* __restrict__ out) {
  const int i = blockIdx.x * 256 + threadIdx.x;
  out[i] = accmu[i] + dmub[0];
  out[OFF_SG_DEC + i] = softplus_(accsg[i] + dstdb[0]);
}

// ---------------------------------------------------------------------------
extern "C" void kernel_launch(void* const* d_in, const int* in_sizes, int n_in,
                              void* d_out, int out_size, void* d_ws, size_t ws_size,
                              hipStream_t stream) {
  (void)in_sizes; (void)n_in; (void)out_size; (void)ws_size;
  const float* x     = (const float*)d_in[0];
  const float* encW  = (const float*)d_in[1];
  const float* encU  = (const float*)d_in[2];
  const float* encb  = (const float*)d_in[3];
  const float* emuW  = (const float*)d_in[4];
  const float* emub  = (const float*)d_in[5];
  const float* estdW = (const float*)d_in[6];
  const float* estdb = (const float*)d_in[7];
  const float* dfsW  = (const float*)d_in[8];
  const float* dfsb  = (const float*)d_in[9];
  const float* decW  = (const float*)d_in[10];
  const float* decU  = (const float*)d_in[11];
  const float* decb  = (const float*)d_in[12];
  const float* dmuW  = (const float*)d_in[13];
  const float* dmub  = (const float*)d_in[14];
  const float* dstdW = (const float*)d_in[15];
  const float* dstdb = (const float*)d_in[16];

  char* ws = (char*)d_ws;
  f16* hbuf    = (f16*)(ws + 0);                        // 1 MB [2][512][512]
  float* accmu = (float*)(ws + (1u << 20));             // 1 MB
  float* accsg = (float*)(ws + (2u << 20));             // 1 MB
  int* flags   = (int*)(ws + (3u << 20));               // 64 KB (2 phases)
  // zin (4 MB) overlays UpkE's region after the encoder is done:
  f16* UpkE    = (f16*)(ws + (3u << 20) + 65536);       // 2 MB (dead post-enc)
  float* zin   = (float*)(ws + (3u << 20) + 65536);     // 4 MB
  f16* UpkD    = (f16*)(ws + (7u << 20) + 65536);       // 2 MB
  float* z     = (float*)(ws + (9u << 20) + 65536);     // 128 KB
  float* out   = (float*)d_out;

  // zero hbuf/acc/flags (must be re-done every launch)
  hipMemsetAsync(d_ws, 0, (3u << 20) + 65536, stream);

  hipLaunchKernelGGL(pack_U, dim3(8192), dim3(256), 0, stream, encU, UpkE);
  hipLaunchKernelGGL(pack_U, dim3(8192), dim3(256), 0, stream, decU, UpkD);

  hipLaunchKernelGGL((lstm_rec<0>), dim3(256), dim3(512), 0, stream,
                     UpkE, x, encW, encb, hbuf, (float*)nullptr, (float*)nullptr,
                     flags);
  hipLaunchKernelGGL(enc_heads, dim3(512), dim3(128), 0, stream,
                     hbuf, emuW, emub, estdW, estdb, out, z);
  hipLaunchKernelGGL(dec_prep, dim3(512), dim3(256), 0, stream,
                     z, dfsW, dfsb, decW, decb, hbuf, zin);
  hipLaunchKernelGGL((lstm_rec<1>), dim3(256), dim3(512), 0, stream,
                     UpkD, zin, dmuW, dstdW, hbuf, accmu, accsg, flags + 8192);
  hipLaunchKernelGGL(finalize_k, dim3(1024), dim3(256), 0, stream,
                     accmu, accsg, dmub, dstdb, out);
}